// Round 8
// baseline (201.470 us; speedup 1.0000x reference)
//
#include <hip/hip_runtime.h>
#include <hip/hip_bf16.h>
#include <math.h>

#define HW    16384
#define Bsz   4
#define CIN   32
#define COUT  64
#define RED   16
#define KKN   49
#define GG    4

typedef __hip_bfloat16 bf16;

__device__ __forceinline__ float gelu_f(float x) {
    return 0.5f * x * (1.0f + erff(x * 0.70710678118654752f));
}
__device__ __forceinline__ void unpack_bf2(unsigned u, float& lo, float& hi) {
    lo = __uint_as_float(u << 16);
    hi = __uint_as_float(u & 0xffff0000u);
}
__device__ __forceinline__ unsigned pack_bf2(float lo, float hi) {
    unsigned a = __float_as_uint(lo), b = __float_as_uint(hi);
    a += 0x7fff + ((a >> 16) & 1);
    b += 0x7fff + ((b >> 16) & 1);
    return (a >> 16) | (b & 0xffff0000u);
}

// K1: x1 = gelu(conv1x1(x, w1)) -> x1b interleaved [b][g][p][c16] bf16
//     r  = relu(bn(conv1x1(x1, wr))) -> rbuf interleaved [b][p][j16] f32
__global__ __launch_bounds__(256, 4) void k1_conv1_gelu_reduce(
    const float* __restrict__ x, const float* __restrict__ w1,
    const float* __restrict__ wr, const float* __restrict__ gr,
    const float* __restrict__ br, const float* __restrict__ mr,
    const float* __restrict__ vr,
    unsigned* __restrict__ x1b, float* __restrict__ rbuf)
{
    __shared__ float g_lds[COUT][65];

    int lane  = threadIdx.x & 63;
    int chunk = __builtin_amdgcn_readfirstlane(threadIdx.x >> 6);  // == group
    int b     = blockIdx.x >> 8;
    int p     = ((blockIdx.x & 255) << 6) + lane;

    float xv[CIN];
#pragma unroll
    for (int c = 0; c < CIN; ++c) xv[c] = x[(b * CIN + c) * HW + p];

    float acc[16];
#pragma unroll
    for (int o = 0; o < 16; ++o) acc[o] = 0.f;
#pragma unroll 8
    for (int c = 0; c < CIN; ++c) {
        float xc = xv[c];
#pragma unroll
        for (int o = 0; o < 16; ++o)
            acc[o] += xc * w1[(chunk * 16 + o) * CIN + c];
    }

    unsigned pk[8];
#pragma unroll
    for (int o = 0; o < 16; ++o) {
        acc[o] = gelu_f(acc[o]);
        g_lds[chunk * 16 + o][lane] = acc[o];
    }
#pragma unroll
    for (int d = 0; d < 8; ++d) pk[d] = pack_bf2(acc[2 * d], acc[2 * d + 1]);
    unsigned* xo = x1b + ((size_t)(b * GG + chunk) * HW + p) * 8;
    *(uint4*)xo       = make_uint4(pk[0], pk[1], pk[2], pk[3]);
    *(uint4*)(xo + 4) = make_uint4(pk[4], pk[5], pk[6], pk[7]);

    __syncthreads();

    float ra[4] = {0.f, 0.f, 0.f, 0.f};
#pragma unroll 8
    for (int c = 0; c < COUT; ++c) {
        float gv = g_lds[c][lane];
#pragma unroll
        for (int jj = 0; jj < 4; ++jj)
            ra[jj] += gv * wr[(chunk * 4 + jj) * COUT + c];
    }
    float4 rv;
    {
        float t[4];
#pragma unroll
        for (int jj = 0; jj < 4; ++jj) {
            int j = chunk * 4 + jj;
            float sc = gr[j] * rsqrtf(vr[j] + 1e-5f);
            float sh = br[j] - mr[j] * sc;
            t[jj] = fmaxf(sc * ra[jj] + sh, 0.f);
        }
        rv = make_float4(t[0], t[1], t[2], t[3]);
    }
    *(float4*)&rbuf[((size_t)b * HW + p) * 16 + chunk * 4] = rv;
}

// K23: per (b,g) block of 256 px. wk[49] in registers (FULL unroll so the
// array is SROA-promoted — partial unroll => dynamic store => scratch spill,
// seen round 7 as VGPR=32 + 50 MB scratch WRITE traffic).
__global__ __launch_bounds__(256, 4) void k23_involution(
    const unsigned* __restrict__ x1b, const float* __restrict__ rbuf,
    const float* __restrict__ wsp, const float* __restrict__ bsp,
    const float* __restrict__ g1, const float* __restrict__ b1,
    const float* __restrict__ m1, const float* __restrict__ v1,
    bf16* __restrict__ x2b)
{
    int bg = blockIdx.x >> 6;
    int g = bg & 3, b = bg >> 2;
    int p = ((blockIdx.x & 63) << 8) + threadIdx.x;
    int h = p >> 7, w0 = p & 127;

    float r[RED];
    {
        const float4* rp = (const float4*)&rbuf[((size_t)b * HW + p) * 16];
        float4 r0 = rp[0], r1 = rp[1], r2 = rp[2], r3 = rp[3];
        r[0]=r0.x; r[1]=r0.y; r[2]=r0.z; r[3]=r0.w;
        r[4]=r1.x; r[5]=r1.y; r[6]=r1.z; r[7]=r1.w;
        r[8]=r2.x; r[9]=r2.y; r[10]=r2.z; r[11]=r2.w;
        r[12]=r3.x; r[13]=r3.y; r[14]=r3.z; r[15]=r3.w;
    }

    const float* wrow = wsp + g * KKN * RED;
    const float* brow = bsp + g * KKN;
    float wk[KKN];
#pragma unroll
    for (int k = 0; k < KKN; ++k) {          // FULL unroll: constant k
        float s = brow[k];
#pragma unroll
        for (int j = 0; j < RED; ++j) s += r[j] * wrow[k * RED + j];
        wk[k] = s;
    }

    const unsigned* xg = x1b + ((size_t)(b * GG + g) * HW) * 8;
    float acc[RED];
#pragma unroll
    for (int c = 0; c < RED; ++c) acc[c] = 0.f;

#pragma unroll
    for (int i = 0; i < 7; ++i) {
        int hh = h + i - 3;                       // wave-uniform
        if ((unsigned)hh < 128u) {
#pragma unroll
            for (int j = 0; j < 7; ++j) {
                int ww = w0 + j - 3;
                if ((unsigned)ww < 128u) {
                    float wv = wk[i * 7 + j];
                    const unsigned* tp = xg + ((size_t)(hh * 128 + ww)) * 8;
                    uint4 A = *(const uint4*)tp;
                    uint4 B = *(const uint4*)(tp + 4);
                    float lo, hi;
                    unpack_bf2(A.x, lo, hi); acc[0] += wv*lo; acc[1] += wv*hi;
                    unpack_bf2(A.y, lo, hi); acc[2] += wv*lo; acc[3] += wv*hi;
                    unpack_bf2(A.z, lo, hi); acc[4] += wv*lo; acc[5] += wv*hi;
                    unpack_bf2(A.w, lo, hi); acc[6] += wv*lo; acc[7] += wv*hi;
                    unpack_bf2(B.x, lo, hi); acc[8] += wv*lo; acc[9] += wv*hi;
                    unpack_bf2(B.y, lo, hi); acc[10]+= wv*lo; acc[11]+= wv*hi;
                    unpack_bf2(B.z, lo, hi); acc[12]+= wv*lo; acc[13]+= wv*hi;
                    unpack_bf2(B.w, lo, hi); acc[14]+= wv*lo; acc[15]+= wv*hi;
                }
            }
        }
    }

#pragma unroll
    for (int c = 0; c < RED; ++c) {
        int ch = g * RED + c;
        float sc = g1[ch] * rsqrtf(v1[ch] + 1e-5f);
        float sh = b1[ch] - m1[ch] * sc;
        x2b[(size_t)(b * COUT + ch) * HW + p] =
            __float2bfloat16(gelu_f(sc * acc[c] + sh));
    }
}

// K4: out = gelu( bn2(conv1x1(x2,w2)) + bnm(conv1x1(x,wm)+bmap) )
__global__ __launch_bounds__(256, 4) void k4_final(
    const bf16* __restrict__ x2b, const float* __restrict__ x,
    const float* __restrict__ w2, const float* __restrict__ g2,
    const float* __restrict__ b2, const float* __restrict__ m2,
    const float* __restrict__ v2,
    const float* __restrict__ wm, const float* __restrict__ bmap,
    const float* __restrict__ gm, const float* __restrict__ betam,
    const float* __restrict__ mm, const float* __restrict__ vm,
    float* __restrict__ out)
{
    int lane  = threadIdx.x & 63;
    int chunk = __builtin_amdgcn_readfirstlane(threadIdx.x >> 6);
    int b     = blockIdx.x >> 8;
    int p     = ((blockIdx.x & 255) << 6) + lane;

    float acc[16];
#pragma unroll
    for (int o = 0; o < 16; ++o) acc[o] = 0.f;

#pragma unroll 8
    for (int c = 0; c < COUT; ++c) {
        float xc = __bfloat162float(x2b[(size_t)(b * COUT + c) * HW + p]);
#pragma unroll
        for (int o = 0; o < 16; ++o)
            acc[o] += xc * w2[(chunk * 16 + o) * COUT + c];
    }
#pragma unroll
    for (int o = 0; o < 16; ++o) {
        int O = chunk * 16 + o;
        float s2 = g2[O] * rsqrtf(v2[O] + 1e-5f);
        float sm = gm[O] * rsqrtf(vm[O] + 1e-5f);
        acc[o] *= s2 / sm;
    }
#pragma unroll 8
    for (int c = 0; c < CIN; ++c) {
        float xc = x[(b * CIN + c) * HW + p];
#pragma unroll
        for (int o = 0; o < 16; ++o)
            acc[o] += xc * wm[(chunk * 16 + o) * CIN + c];
    }
#pragma unroll
    for (int o = 0; o < 16; ++o) {
        int O = chunk * 16 + o;
        float s2 = g2[O] * rsqrtf(v2[O] + 1e-5f);
        float sm = gm[O] * rsqrtf(vm[O] + 1e-5f);
        float shc = (b2[O] - m2[O] * s2)
                  + (betam[O] + (bmap[O] - mm[O]) * sm);
        out[(size_t)(b * COUT + O) * HW + p] = gelu_f(sm * acc[o] + shc);
    }
}

extern "C" void kernel_launch(void* const* d_in, const int* in_sizes, int n_in,
                              void* d_out, int out_size, void* d_ws, size_t ws_size,
                              hipStream_t stream) {
    const float* x    = (const float*)d_in[0];
    const float* w1   = (const float*)d_in[1];
    const float* wr   = (const float*)d_in[2];
    const float* gr   = (const float*)d_in[3];
    const float* br   = (const float*)d_in[4];
    const float* mr   = (const float*)d_in[5];
    const float* vr   = (const float*)d_in[6];
    const float* wsp  = (const float*)d_in[7];
    const float* bsp  = (const float*)d_in[8];
    const float* g1   = (const float*)d_in[9];
    const float* b1   = (const float*)d_in[10];
    const float* m1   = (const float*)d_in[11];
    const float* v1   = (const float*)d_in[12];
    const float* w2   = (const float*)d_in[13];
    const float* g2   = (const float*)d_in[14];
    const float* b2   = (const float*)d_in[15];
    const float* m2   = (const float*)d_in[16];
    const float* v2   = (const float*)d_in[17];
    const float* wm   = (const float*)d_in[18];
    const float* bmap = (const float*)d_in[19];
    const float* gm   = (const float*)d_in[20];
    const float* betam= (const float*)d_in[21];
    const float* mm   = (const float*)d_in[22];
    const float* vm   = (const float*)d_in[23];

    // workspace:
    //   x1b  bf16 interleaved [b][g][p][c16]  8,388,608 B @ 0
    //   rbuf f32  interleaved [b][p][j16]     4,194,304 B @ 8,388,608
    //   x2b  bf16 planar      [b][ch][p]      8,388,608 B @ 12,582,912
    unsigned* x1b  = (unsigned*)d_ws;
    float*    rbuf = (float*)((char*)d_ws + 8388608);
    bf16*     x2b  = (bf16*)((char*)d_ws + 12582912);

    k1_conv1_gelu_reduce<<<Bsz * HW / 64, 256, 0, stream>>>(
        x, w1, wr, gr, br, mr, vr, x1b, rbuf);
    k23_involution<<<Bsz * GG * HW / 256, 256, 0, stream>>>(
        x1b, rbuf, wsp, bsp, g1, b1, m1, v1, x2b);
    k4_final<<<Bsz * HW / 64, 256, 0, stream>>>(
        x2b, x, w2, g2, b2, m2, v2, wm, bmap, gm, betam, mm, vm,
        (float*)d_out);
}